// Round 3
// baseline (257.325 us; speedup 1.0000x reference)
//
#include <hip/hip_runtime.h>

#define BATCH 32
#define H 512
#define W 512
#define PAD 4
#define WIN 9
#define SEG 32                      // output rows per block
#define NSTEP (SEG + WIN - 1)       // 40 row-steps
// final scalar = sum over pixels of ((1-cc1)+(1-cc2)) * 0.5 / (B*H*W)
#define SCALE (0.5f / 8388608.0f)

__global__ __launch_bounds__(256) void ncc_loss_kernel(
    const float* __restrict__ g1, const float* __restrict__ g2,
    const float* __restrict__ gf, float* __restrict__ out)
{
    const int t  = threadIdx.x;
    const int x  = blockIdx.x * 256 + t;             // column
    const int y0 = blockIdx.y * SEG;                 // output row band start
    const int b  = blockIdx.z;
    const size_t base = (size_t)b * (H * W);
    const float* I1 = g1 + base;
    const float* I2 = g2 + base;
    const float* F  = gf + base;

    // Per-thread clamped horizontal tap offsets + zero-masks, computed ONCE.
    // Loads become unconditional (clamped address is always valid); the mask
    // zeroes the contribution of out-of-range taps (only 8 edge lanes/image row).
    int   off[WIN];
    float m[WIN];
#pragma unroll
    for (int k = 0; k < WIN; ++k) {
        const int xx = x + k - PAD;
        const bool ok = ((unsigned)xx < (unsigned)W);
        off[k] = ok ? xx : (xx < 0 ? 0 : W - 1);
        m[k]   = ok ? 1.0f : 0.0f;
    }

    // 9-deep register ring of horizontal 9-sums (ring idx = compile-time ph).
    // NOTE: must stay in VGPRs — no __launch_bounds__ min-waves arg (r2 spilled).
    float r1[WIN], r2[WIN], rf[WIN], r11[WIN], r22[WIN], rff[WIN], r1f[WIN], r2f[WIN];
#pragma unroll
    for (int i = 0; i < WIN; ++i) {
        r1[i]=0.f; r2[i]=0.f; rf[i]=0.f; r11[i]=0.f;
        r22[i]=0.f; rff[i]=0.f; r1f[i]=0.f; r2f[i]=0.f;
    }
    float v1=0.f,v2=0.f,vf=0.f,v11=0.f,v22=0.f,vff=0.f,v1f=0.f,v2f=0.f;
    float lsum = 0.f;
    const float inv_n = 1.0f / 81.0f;

    auto do_step = [&](int step, int ph) {           // ph compile-time constant
        const int yr = y0 - PAD + step;              // incoming raw row
        float s1=0.f,s2=0.f,sf=0.f,s11=0.f,s22=0.f,sff=0.f,s1f=0.f,s2f=0.f;
        if (yr >= 0 && yr < H) {                     // wave-uniform (zero v-pad)
            const float* p1 = I1 + (size_t)yr * W;   // uniform row base -> SGPR
            const float* p2 = I2 + (size_t)yr * W;
            const float* pf = F  + (size_t)yr * W;
#pragma unroll
            for (int k = 0; k < WIN; ++k) {
                const float a = p1[off[k]];
                const float c = p2[off[k]];
                const float f = pf[off[k]];
                const float am = a * m[k];           // masked factors; products
                const float cm = c * m[k];           // inherit the mask
                const float fm = f * m[k];
                s1 += am; s2 += cm; sf += fm;
                s11 = fmaf(am, a, s11);
                s22 = fmaf(cm, c, s22);
                sff = fmaf(fm, f, sff);
                s1f = fmaf(am, f, s1f);
                s2f = fmaf(cm, f, s2f);
            }
        }
        // vertical sliding window via register ring
        v1  += s1  - r1[ph];  r1[ph]  = s1;
        v2  += s2  - r2[ph];  r2[ph]  = s2;
        vf  += sf  - rf[ph];  rf[ph]  = sf;
        v11 += s11 - r11[ph]; r11[ph] = s11;
        v22 += s22 - r22[ph]; r22[ph] = s22;
        vff += sff - rff[ph]; rff[ph] = sff;
        v1f += s1f - r1f[ph]; r1f[ph] = s1f;
        v2f += s2f - r2f[ph]; r2f[ph] = s2f;

        if (step >= WIN - 1) {                       // emit output row yr - PAD
            const float u1 = v1 * inv_n, u2 = v2 * inv_n, uf = vf * inv_n;
            const float cross1 = fmaf(-v1, uf, v1f);
            const float var1   = fmaf(-v1, u1, v11);
            const float varf   = fmaf(-vf, uf, vff);
            const float cross2 = fmaf(-v2, uf, v2f);
            const float var2   = fmaf(-v2, u2, v22);
            const float d1 = fmaf(var1, varf, 1e-5f);
            const float d2 = fmaf(var2, varf, 1e-5f);
            // cc1 + cc2 = (cross1^2*d2 + cross2^2*d1) / (d1*d2): single rcp
            const float inv = __builtin_amdgcn_rcpf(d1 * d2);
            float num = cross1 * cross1 * d2;
            num = fmaf(cross2 * cross2, d1, num);
            lsum += fmaf(-num, inv, 2.0f);           // (1-cc1)+(1-cc2)
        }
    };

    // 40 steps = 4 x 9 phases + 4 tail (36 % 9 == 0 so ring idx == ph)
#pragma unroll 1
    for (int os = 0; os < NSTEP / WIN; ++os) {
#pragma unroll
        for (int ph = 0; ph < WIN; ++ph) do_step(os * WIN + ph, ph);
    }
#pragma unroll
    for (int ph = 0; ph < NSTEP % WIN; ++ph) do_step((NSTEP / WIN) * WIN + ph, ph);

    // block reduction: wave shuffle -> LDS -> one atomic per block
#pragma unroll
    for (int offd = 32; offd > 0; offd >>= 1)
        lsum += __shfl_down(lsum, offd);
    __shared__ float wsum[4];
    const int lane = threadIdx.x & 63;
    const int wid  = threadIdx.x >> 6;
    if (lane == 0) wsum[wid] = lsum;
    __syncthreads();
    if (threadIdx.x == 0) {
        atomicAdd(out, (wsum[0] + wsum[1] + wsum[2] + wsum[3]) * SCALE);
    }
}

extern "C" void kernel_launch(void* const* d_in, const int* in_sizes, int n_in,
                              void* d_out, int out_size, void* d_ws, size_t ws_size,
                              hipStream_t stream) {
    const float* img1 = (const float*)d_in[0];
    const float* img2 = (const float*)d_in[1];
    const float* fimg = (const float*)d_in[2];
    float* out = (float*)d_out;

    hipMemsetAsync(out, 0, sizeof(float), stream);  // d_out re-poisoned each call

    dim3 grid(W / 256, H / SEG, BATCH);   // (2, 16, 32) = 1024 blocks
    ncc_loss_kernel<<<grid, dim3(256), 0, stream>>>(img1, img2, fimg, out);
}

// Round 4
// 164.506 us; speedup vs baseline: 1.5642x; 1.5642x over previous
//
#include <hip/hip_runtime.h>

#define BATCH 32
#define H 512
#define W 512
#define PAD 4
#define WIN 9
#define SEG 32                      // output rows per block
#define NSTEP (SEG + WIN - 1)       // 40 row-steps
// final scalar = sum over pixels of ((1-cc1)+(1-cc2)) * 0.5 / (B*H*W)
#define SCALE (0.5f / 8388608.0f)

__global__ __launch_bounds__(256) void ncc_loss_kernel(
    const float* __restrict__ g1, const float* __restrict__ g2,
    const float* __restrict__ gf, float* __restrict__ out)
{
    const int t  = threadIdx.x;
    const int x  = blockIdx.x * 256 + t;             // column
    const int y0 = blockIdx.y * SEG;                 // output row band start
    const int b  = blockIdx.z;
    const size_t base = (size_t)b * (H * W);

    // Single per-lane byte offset; the 9 taps use voff + k*4 (imm-offset field).
    // OOB (x<4 left edge / x>507 right edge) wraps unsigned -> SRD bounds check
    // fails -> hardware returns 0.0f == the conv zero-padding. No masks.
    const int voff = x * 4 - PAD * 4;

    // 9-deep register ring of horizontal 9-sums (ring idx = compile-time ph).
    float r1[WIN], r2[WIN], rf[WIN], r11[WIN], r22[WIN], rff[WIN], r1f[WIN], r2f[WIN];
#pragma unroll
    for (int i = 0; i < WIN; ++i) {
        r1[i]=0.f; r2[i]=0.f; rf[i]=0.f; r11[i]=0.f;
        r22[i]=0.f; rff[i]=0.f; r1f[i]=0.f; r2f[i]=0.f;
    }
    float v1=0.f,v2=0.f,vf=0.f,v11=0.f,v22=0.f,vff=0.f,v1f=0.f,v2f=0.f;
    float lsum = 0.f;
    const float inv_n = 1.0f / 81.0f;

    auto do_step = [&](int step, int ph) {           // ph compile-time constant
        const int yr = y0 - PAD + step;              // incoming raw row
        // vertical padding: num_records=0 for OOB rows -> all loads return 0
        const int rec = ((unsigned)yr < (unsigned)H) ? (W * 4) : 0;
        const int yc  = yr < 0 ? 0 : (yr >= H ? H - 1 : yr);  // safe base
        const size_t roff = base + (size_t)yc * W;   // all wave-uniform scalars
        __amdgpu_buffer_rsrc_t s1r = __builtin_amdgcn_make_buffer_rsrc(
            (void*)(g1 + roff), (short)0, rec, 0x00020000);
        __amdgpu_buffer_rsrc_t s2r = __builtin_amdgcn_make_buffer_rsrc(
            (void*)(g2 + roff), (short)0, rec, 0x00020000);
        __amdgpu_buffer_rsrc_t sfr = __builtin_amdgcn_make_buffer_rsrc(
            (void*)(gf + roff), (short)0, rec, 0x00020000);

        // issue all 27 independent loads first (batched, vmcnt-overlapped)
        float a[WIN], c[WIN], f[WIN];
#pragma unroll
        for (int k = 0; k < WIN; ++k) {
            a[k] = __builtin_bit_cast(float,
                __builtin_amdgcn_raw_buffer_load_b32(s1r, voff + k * 4, 0, 0));
            c[k] = __builtin_bit_cast(float,
                __builtin_amdgcn_raw_buffer_load_b32(s2r, voff + k * 4, 0, 0));
            f[k] = __builtin_bit_cast(float,
                __builtin_amdgcn_raw_buffer_load_b32(sfr, voff + k * 4, 0, 0));
        }

        // horizontal 9-tap sums of the 8 quantities
        float s1=0.f,s2=0.f,sf=0.f,s11=0.f,s22=0.f,sff=0.f,s1f=0.f,s2f=0.f;
#pragma unroll
        for (int k = 0; k < WIN; ++k) {
            s1 += a[k]; s2 += c[k]; sf += f[k];
            s11 = fmaf(a[k], a[k], s11);
            s22 = fmaf(c[k], c[k], s22);
            sff = fmaf(f[k], f[k], sff);
            s1f = fmaf(a[k], f[k], s1f);
            s2f = fmaf(c[k], f[k], s2f);
        }

        // vertical sliding window via register ring
        v1  += s1  - r1[ph];  r1[ph]  = s1;
        v2  += s2  - r2[ph];  r2[ph]  = s2;
        vf  += sf  - rf[ph];  rf[ph]  = sf;
        v11 += s11 - r11[ph]; r11[ph] = s11;
        v22 += s22 - r22[ph]; r22[ph] = s22;
        vff += sff - rff[ph]; rff[ph] = sff;
        v1f += s1f - r1f[ph]; r1f[ph] = s1f;
        v2f += s2f - r2f[ph]; r2f[ph] = s2f;

        if (step >= WIN - 1) {                       // emit output row yr - PAD
            const float u1 = v1 * inv_n, u2 = v2 * inv_n, uf = vf * inv_n;
            const float cross1 = fmaf(-v1, uf, v1f);
            const float var1   = fmaf(-v1, u1, v11);
            const float varf   = fmaf(-vf, uf, vff);
            const float cross2 = fmaf(-v2, uf, v2f);
            const float var2   = fmaf(-v2, u2, v22);
            const float d1 = fmaf(var1, varf, 1e-5f);
            const float d2 = fmaf(var2, varf, 1e-5f);
            // cc1 + cc2 = (cross1^2*d2 + cross2^2*d1) / (d1*d2): single rcp
            const float inv = __builtin_amdgcn_rcpf(d1 * d2);
            float num = cross1 * cross1 * d2;
            num = fmaf(cross2 * cross2, d1, num);
            lsum += fmaf(-num, inv, 2.0f);           // (1-cc1)+(1-cc2)
        }
    };

    // 40 steps = 4 x 9 phases + 4 tail (36 % 9 == 0 so ring idx == ph)
#pragma unroll 1
    for (int os = 0; os < NSTEP / WIN; ++os) {
#pragma unroll
        for (int ph = 0; ph < WIN; ++ph) do_step(os * WIN + ph, ph);
    }
#pragma unroll
    for (int ph = 0; ph < NSTEP % WIN; ++ph) do_step((NSTEP / WIN) * WIN + ph, ph);

    // block reduction: wave shuffle -> LDS -> one atomic per block
#pragma unroll
    for (int offd = 32; offd > 0; offd >>= 1)
        lsum += __shfl_down(lsum, offd);
    __shared__ float wsum[4];
    const int lane = threadIdx.x & 63;
    const int wid  = threadIdx.x >> 6;
    if (lane == 0) wsum[wid] = lsum;
    __syncthreads();
    if (threadIdx.x == 0) {
        atomicAdd(out, (wsum[0] + wsum[1] + wsum[2] + wsum[3]) * SCALE);
    }
}

extern "C" void kernel_launch(void* const* d_in, const int* in_sizes, int n_in,
                              void* d_out, int out_size, void* d_ws, size_t ws_size,
                              hipStream_t stream) {
    const float* img1 = (const float*)d_in[0];
    const float* img2 = (const float*)d_in[1];
    const float* fimg = (const float*)d_in[2];
    float* out = (float*)d_out;

    hipMemsetAsync(out, 0, sizeof(float), stream);  // d_out re-poisoned each call

    dim3 grid(W / 256, H / SEG, BATCH);   // (2, 16, 32) = 1024 blocks
    ncc_loss_kernel<<<grid, dim3(256), 0, stream>>>(img1, img2, fimg, out);
}

// Round 5
// 160.032 us; speedup vs baseline: 1.6080x; 1.0280x over previous
//
#include <hip/hip_runtime.h>

#define BATCH 32
#define H 512
#define W 512
#define PAD 4
#define WIN 9
#define SEG 16                      // output rows per block
#define NSTEP (SEG + WIN - 1)       // 24 row-steps, fully unrolled
// final scalar = sum over pixels of ((1-cc1)+(1-cc2)) * 0.5 / (B*H*W)
#define SCALE (0.5f / 8388608.0f)

__global__ __launch_bounds__(256) void ncc_loss_kernel(
    const float* __restrict__ g1, const float* __restrict__ g2,
    const float* __restrict__ gf, float* __restrict__ out)
{
    const int t  = threadIdx.x;
    const int x  = blockIdx.x * 256 + t;             // column
    const int y0 = blockIdx.y * SEG;                 // output row band start
    const int b  = blockIdx.z;
    const size_t base = (size_t)b * (H * W);

    // Single per-lane byte offset; taps use voff + k*4 (imm-offset field).
    // OOB columns wrap unsigned -> SRD bounds check fails -> hardware 0.0f.
    const int voff = x * 4 - PAD * 4;

    // Double-buffered prefetch registers: [parity][image][tap].
    float buf[2][3][WIN];

    // Issue all 27 loads for row-step `step` into buf[parity].
    // Vertical padding: num_records=0 for OOB rows -> loads return 0.
    auto load_row = [&](int step, int parity) {
        const int yr  = y0 - PAD + step;
        const int rec = ((unsigned)yr < (unsigned)H) ? (W * 4) : 0;
        const int yc  = yr < 0 ? 0 : (yr >= H ? H - 1 : yr);   // safe base
        const size_t roff = base + (size_t)yc * W;             // wave-uniform
        __amdgpu_buffer_rsrc_t s1r = __builtin_amdgcn_make_buffer_rsrc(
            (void*)(g1 + roff), (short)0, rec, 0x00020000);
        __amdgpu_buffer_rsrc_t s2r = __builtin_amdgcn_make_buffer_rsrc(
            (void*)(g2 + roff), (short)0, rec, 0x00020000);
        __amdgpu_buffer_rsrc_t sfr = __builtin_amdgcn_make_buffer_rsrc(
            (void*)(gf + roff), (short)0, rec, 0x00020000);
#pragma unroll
        for (int k = 0; k < WIN; ++k) {
            buf[parity][0][k] = __builtin_bit_cast(float,
                __builtin_amdgcn_raw_buffer_load_b32(s1r, voff + k * 4, 0, 0));
            buf[parity][1][k] = __builtin_bit_cast(float,
                __builtin_amdgcn_raw_buffer_load_b32(s2r, voff + k * 4, 0, 0));
            buf[parity][2][k] = __builtin_bit_cast(float,
                __builtin_amdgcn_raw_buffer_load_b32(sfr, voff + k * 4, 0, 0));
        }
    };

    // 9-deep register ring of horizontal 9-sums (ring idx compile-time).
    float r1[WIN], r2[WIN], rf[WIN], r11[WIN], r22[WIN], rff[WIN], r1f[WIN], r2f[WIN];
#pragma unroll
    for (int i = 0; i < WIN; ++i) {
        r1[i]=0.f; r2[i]=0.f; rf[i]=0.f; r11[i]=0.f;
        r22[i]=0.f; rff[i]=0.f; r1f[i]=0.f; r2f[i]=0.f;
    }
    float v1=0.f,v2=0.f,vf=0.f,v11=0.f,v22=0.f,vff=0.f,v1f=0.f,v2f=0.f;
    float lsum = 0.f;
    const float inv_n = 1.0f / 81.0f;

    load_row(0, 0);                                  // prologue prefetch

    // Fully unrolled software pipeline: issue step s+1's loads, then
    // consume step s's registers (compute covers the load latency).
#pragma unroll
    for (int s = 0; s < NSTEP; ++s) {
        if (s + 1 < NSTEP) load_row(s + 1, (s + 1) & 1);   // compile-time guard

        const float* a = buf[s & 1][0];
        const float* c = buf[s & 1][1];
        const float* f = buf[s & 1][2];

        // horizontal 9-tap sums of the 8 quantities
        float s1=0.f,s2=0.f,sf=0.f,s11=0.f,s22=0.f,sff=0.f,s1f=0.f,s2f=0.f;
#pragma unroll
        for (int k = 0; k < WIN; ++k) {
            s1 += a[k]; s2 += c[k]; sf += f[k];
            s11 = fmaf(a[k], a[k], s11);
            s22 = fmaf(c[k], c[k], s22);
            sff = fmaf(f[k], f[k], sff);
            s1f = fmaf(a[k], f[k], s1f);
            s2f = fmaf(c[k], f[k], s2f);
        }

        // vertical sliding window via register ring (ph compile-time)
        const int ph = s % WIN;
        v1  += s1  - r1[ph];  r1[ph]  = s1;
        v2  += s2  - r2[ph];  r2[ph]  = s2;
        vf  += sf  - rf[ph];  rf[ph]  = sf;
        v11 += s11 - r11[ph]; r11[ph] = s11;
        v22 += s22 - r22[ph]; r22[ph] = s22;
        vff += sff - rff[ph]; rff[ph] = sff;
        v1f += s1f - r1f[ph]; r1f[ph] = s1f;
        v2f += s2f - r2f[ph]; r2f[ph] = s2f;

        if (s >= WIN - 1) {                          // emit output row y0+s-8
            const float u1 = v1 * inv_n, u2 = v2 * inv_n, uf = vf * inv_n;
            const float cross1 = fmaf(-v1, uf, v1f);
            const float var1   = fmaf(-v1, u1, v11);
            const float varf   = fmaf(-vf, uf, vff);
            const float cross2 = fmaf(-v2, uf, v2f);
            const float var2   = fmaf(-v2, u2, v22);
            const float d1 = fmaf(var1, varf, 1e-5f);
            const float d2 = fmaf(var2, varf, 1e-5f);
            // cc1 + cc2 = (cross1^2*d2 + cross2^2*d1) / (d1*d2): single rcp
            const float inv = __builtin_amdgcn_rcpf(d1 * d2);
            float num = cross1 * cross1 * d2;
            num = fmaf(cross2 * cross2, d1, num);
            lsum += fmaf(-num, inv, 2.0f);           // (1-cc1)+(1-cc2)
        }
    }

    // block reduction: wave shuffle -> LDS -> one atomic per block
#pragma unroll
    for (int offd = 32; offd > 0; offd >>= 1)
        lsum += __shfl_down(lsum, offd);
    __shared__ float wsum[4];
    const int lane = threadIdx.x & 63;
    const int wid  = threadIdx.x >> 6;
    if (lane == 0) wsum[wid] = lsum;
    __syncthreads();
    if (threadIdx.x == 0) {
        atomicAdd(out, (wsum[0] + wsum[1] + wsum[2] + wsum[3]) * SCALE);
    }
}

extern "C" void kernel_launch(void* const* d_in, const int* in_sizes, int n_in,
                              void* d_out, int out_size, void* d_ws, size_t ws_size,
                              hipStream_t stream) {
    const float* img1 = (const float*)d_in[0];
    const float* img2 = (const float*)d_in[1];
    const float* fimg = (const float*)d_in[2];
    float* out = (float*)d_out;

    hipMemsetAsync(out, 0, sizeof(float), stream);  // d_out re-poisoned each call

    dim3 grid(W / 256, H / SEG, BATCH);   // (2, 32, 32) = 2048 blocks
    ncc_loss_kernel<<<grid, dim3(256), 0, stream>>>(img1, img2, fimg, out);
}